// Round 7
// baseline (1826.215 us; speedup 1.0000x reference)
//
#include <hip/hip_runtime.h>
#include <hip/hip_bf16.h>
#include <hip/hip_fp16.h>

// ---------------------------------------------------------------------------
// 3-layer GRU (Keras v2, reset_after=True), B=64 T=2048 F=H=128, OUT=5.
// Round 7: stall removal inside the r6 layer-pipelined persistent kernel.
//   r6 counters: VALUBusy ~60% on active CUs, step ~2000cy vs ~660cy issue
//   floor -> 40% stall. Fixes:
//   1. proj input row register-prefetched 1 step ahead (ip[2][4] f16x8):
//      proj dots never touch LDS at step start; ipre LDS load has ~700cy slack.
//   2. __launch_bounds__(512,1): grid 192 < 256 CUs -> always 1 WG/CU; free
//      the VGPR budget (256) for deeper compiler scheduling.
//   3. Explicit order: rec dots -> proj dots(regs) -> ipre load -> rec reduce
//      -> gates -> writes -> proj reduce -> soft barrier.
// ---------------------------------------------------------------------------

#define HID   128
#define H3    384
#define OUTD  5
#define CHK   16            // steps per chunk (publish/poll granularity)

typedef _Float16 f16x2 __attribute__((ext_vector_type(2)));
typedef _Float16 f16x8 __attribute__((ext_vector_type(8)));

__device__ __forceinline__ float fdot2(f16x2 a, f16x2 b, float c) {
#if __has_builtin(__builtin_amdgcn_fdot2)
    return __builtin_amdgcn_fdot2(a, b, c, false);   // v_dot2_f32_f16
#else
    return fmaf((float)a.x, (float)b.x, fmaf((float)a.y, (float)b.y, c));
#endif
}

__device__ __forceinline__ float fexp2(float x) {
#if __has_builtin(__builtin_amdgcn_exp2f)
    return __builtin_amdgcn_exp2f(x);
#else
    return exp2f(x);
#endif
}

__device__ __forceinline__ float frcp(float x) {
#if __has_builtin(__builtin_amdgcn_rcpf)
    return __builtin_amdgcn_rcpf(x);
#else
    return 1.f / x;
#endif
}

// sigmoid(x) = 1/(1+exp(-x)); saturates correctly at +-inf.
__device__ __forceinline__ float fsigmoid(float x) {
    return frcp(1.f + fexp2(x * -1.4426950408889634f));
}

// tanh(x) = 1 - 2/(1+exp(2x)); saturates correctly at +-inf.
__device__ __forceinline__ float ftanh_(float x) {
    return fmaf(-2.f, frcp(1.f + fexp2(x * 2.8853900817779268f)), 1.f);
}

// barrier that does NOT drain vmcnt (unlike __syncthreads): LDS handoff only.
__device__ __forceinline__ void soft_barrier() {
    asm volatile("s_waitcnt lgkmcnt(0)\n\ts_barrier" ::: "memory");
}

// butterfly sum over the kh quad (lanes xor 1, xor 2) on the VALU pipe
__device__ __forceinline__ float quad_sum(float x) {
#if __has_builtin(__builtin_amdgcn_mov_dpp)
    int i1 = __builtin_amdgcn_mov_dpp(__float_as_int(x), 0xB1, 0xF, 0xF, true); // [1,0,3,2]
    x += __int_as_float(i1);
    int i2 = __builtin_amdgcn_mov_dpp(__float_as_int(x), 0x4E, 0xF, 0xF, true); // [2,3,0,1]
    x += __int_as_float(i2);
#else
    x += __shfl_xor(x, 1);
    x += __shfl_xor(x, 2);
#endif
    return x;
}

// ---------------------------------------------------------------------------
__global__ void zero_flags(int* f) {
    if (threadIdx.x < 192) f[threadIdx.x] = 0;
}

// ---------------------------------------------------------------------------
// gru_pipe: 192 WGs = 3 layers x 64 batches, 512 thr (8 waves, 2/SIMD).
// Thread (j = t>>2, kh = t&3): unit j, k-quarter kh.
// ---------------------------------------------------------------------------
__global__ __launch_bounds__(512, 1) void gru_pipe(
    const float* __restrict__ x,                         // [64,T,128] fp32
    const float* __restrict__ k0, const float* __restrict__ k1, const float* __restrict__ k2,
    const float* __restrict__ rk0, const float* __restrict__ rk1, const float* __restrict__ rk2,
    const float* __restrict__ b0, const float* __restrict__ b1, const float* __restrict__ b2,
    _Float16* __restrict__ hpl0, _Float16* __restrict__ hpl1, _Float16* __restrict__ hpl2,
    int* flags, int T)
{
    const int blk   = blockIdx.x;
    const int layer = blk >> 6;       // 0..2
    const int b     = blk & 63;       // batch
    const int t     = threadIdx.x;    // 0..511
    const int j     = t >> 2;         // unit 0..127
    const int kh    = t & 3;          // k-quarter
    const int k0i   = kh * 32;
    const int NC    = T / CHK;        // 128 chunks

    const float* Kw = (layer == 0) ? k0  : (layer == 1) ? k1  : k2;
    const float* Rw = (layer == 0) ? rk0 : (layer == 1) ? rk1 : rk2;
    const float* Bs = (layer == 0) ? b0  : (layer == 1) ? b1  : b2;
    const _Float16* hin = (layer == 1) ? hpl0 : hpl1;    // unused for layer 0
    _Float16* hout = (layer == 0) ? hpl0 : (layer == 1) ? hpl1 : hpl2;

    __shared__ __align__(16) _Float16 hb[2][HID];        // own-state dbuf
    __shared__ __align__(16) _Float16 ins[2][CHK][HID];  // staged input rows

    // resident weights: recurrent + input, 3 gates x 16 f16x2 each = 96 VGPRs
    f16x2 wzR[16], wrR[16], whR[16], wzK[16], wrK[16], whK[16];
#pragma unroll
    for (int p = 0; p < 16; ++p) {
        const int k = k0i + 2 * p;
        const float* r0p = Rw + (size_t)k * H3;
        const float* r1p = Rw + (size_t)(k + 1) * H3;
        const float* k0p = Kw + (size_t)k * H3;
        const float* k1p = Kw + (size_t)(k + 1) * H3;
        f16x2 a;
        a.x = (_Float16)r0p[j];       a.y = (_Float16)r1p[j];       wzR[p] = a;
        a.x = (_Float16)r0p[j + 128]; a.y = (_Float16)r1p[j + 128]; wrR[p] = a;
        a.x = (_Float16)r0p[j + 256]; a.y = (_Float16)r1p[j + 256]; whR[p] = a;
        a.x = (_Float16)k0p[j];       a.y = (_Float16)k1p[j];       wzK[p] = a;
        a.x = (_Float16)k0p[j + 128]; a.y = (_Float16)k1p[j + 128]; wrK[p] = a;
        a.x = (_Float16)k0p[j + 256]; a.y = (_Float16)k1p[j + 256]; whK[p] = a;
    }
    const float bzK = Bs[j]       + Bs[384 + j];         // b_in(z)+b_rec(z)
    const float brK = Bs[128 + j] + Bs[384 + 128 + j];   // b_in(r)+b_rec(r)
    const float bhK = Bs[256 + j];                       // b_in(h)
    const float bhR = Bs[384 + 256 + j];                 // b_rec(h) (inside r*)

    int* myflag = flags + layer * 64 + b;
    int* sflag  = flags + (layer - 1) * 64 + b;

    const float*    xb  = x    + (size_t)b * T * HID;
    const _Float16* hib = hin  + (size_t)b * T * HID;
    _Float16*       hob = hout + (size_t)b * T * HID;

    // ---- staging helpers: chunk = CHK rows x 128 f16 = 1024 f16x2 dwords ----
    f16x2 sreg[2];
    auto stage_load = [&](int cc) {
#pragma unroll
        for (int i = 0; i < 2; ++i) {
            const int d  = t + 512 * i;
            const int rw = d >> 6;
            const int c2 = d & 63;
            const size_t off = (size_t)(cc * CHK + rw) * HID + 2 * c2;
            if (layer == 0) {
                const float2 v = *(const float2*)(xb + off);
                f16x2 o; o.x = (_Float16)v.x; o.y = (_Float16)v.y;
                sreg[i] = o;
            } else {
                sreg[i] = *(const f16x2*)(hib + off);
            }
        }
    };
    auto stage_write = [&](int cc) {
        const int slot = cc & 1;
#pragma unroll
        for (int i = 0; i < 2; ++i) {
            const int d  = t + 512 * i;
            const int rw = d >> 6;
            const int c2 = d & 63;
            *(f16x2*)(&ins[slot][rw][2 * c2]) = sreg[i];
        }
    };

    if (t < HID) { hb[0][t] = (_Float16)0.f; hb[1][t] = (_Float16)0.f; }

    // ---- prologue: chunk 0 staged + proj[0] + ipre for row 1 ----
    if (layer > 0 && t == 0) {
        while (__hip_atomic_load(sflag, __ATOMIC_ACQUIRE, __HIP_MEMORY_SCOPE_AGENT) < CHK)
            __builtin_amdgcn_s_sleep(4);
    }
    __syncthreads();
    stage_load(0);
    stage_write(0);      // vmcnt wait here (prologue only)
    __syncthreads();

    float xz, xr, xh;
    {
        const f16x8* ip0 = (const f16x8*)(&ins[0][0][k0i]);
        float pz = 0.f, pr = 0.f, ph = 0.f;
#pragma unroll
        for (int i = 0; i < 4; ++i) {
            union { f16x8 v; f16x2 p[4]; } u;
            u.v = ip0[i];
#pragma unroll
            for (int q = 0; q < 4; ++q) {
                pz = fdot2(u.p[q], wzK[4 * i + q], pz);
                pr = fdot2(u.p[q], wrK[4 * i + q], pr);
                ph = fdot2(u.p[q], whK[4 * i + q], ph);
            }
        }
        xz = quad_sum(pz) + bzK;
        xr = quad_sum(pr) + brK;
        xh = quad_sum(ph) + bhK;
    }

    // proj-input register prefetch: ip[s] holds ins row consumed at step with
    // (ts&1)==s (row tstep+1 for the proj of tstep+1).
    f16x8 ip[2][4];
    {
        const f16x8* p1 = (const f16x8*)(&ins[0][1][k0i]);
#pragma unroll
        for (int i = 0; i < 4; ++i) ip[0][i] = p1[i];
    }

    float h_old = 0.f;

    // ---- main loop over chunks ----
    for (int c = 0; c < NC; ++c) {
        __syncthreads();   // full drain: h stores of prev chunk complete
        if (t == 0) {
            if (layer < 2 && c > 0)
                __hip_atomic_store(myflag, c * CHK, __ATOMIC_RELEASE, __HIP_MEMORY_SCOPE_AGENT);
            if (layer > 0 && c + 1 < NC) {
                while (__hip_atomic_load(sflag, __ATOMIC_ACQUIRE, __HIP_MEMORY_SCOPE_AGENT) < (c + 2) * CHK)
                    __builtin_amdgcn_s_sleep(4);
            }
        }
        __syncthreads();
        if (c + 1 < NC) stage_load(c + 1);   // in flight until ts==7 ds_write

#pragma unroll 2
        for (int ts = 0; ts < CHK; ++ts) {
            const int tstep = c * CHK + ts;
            const int rbuf  = ts & 1;
            const int cur   = ts & 1;

            // (1) recurrent dots from own h state (LDS, post-barrier)
            const f16x8* hp = (const f16x8*)(&hb[rbuf][k0i]);
            float sz = 0.f, sr = 0.f, sh = 0.f;
#pragma unroll
            for (int i = 0; i < 4; ++i) {
                union { f16x8 v; f16x2 p[4]; } u;
                u.v = hp[i];
#pragma unroll
                for (int q = 0; q < 4; ++q) {
                    sz = fdot2(u.p[q], wzR[4 * i + q], sz);
                    sr = fdot2(u.p[q], wrR[4 * i + q], sr);
                    sh = fdot2(u.p[q], whR[4 * i + q], sh);
                }
            }

            // (2) proj dots for step tstep+1 from REGISTERS (independent filler)
            float pz = 0.f, pr = 0.f, ph = 0.f;
            if (tstep + 1 < T) {
#pragma unroll
                for (int i = 0; i < 4; ++i) {
                    union { f16x8 v; f16x2 p[4]; } u;
                    u.v = ip[cur][i];
#pragma unroll
                    for (int q = 0; q < 4; ++q) {
                        pz = fdot2(u.p[q], wzK[4 * i + q], pz);
                        pr = fdot2(u.p[q], wrK[4 * i + q], pr);
                        ph = fdot2(u.p[q], whK[4 * i + q], ph);
                    }
                }
            }

            // (3) ipre load for row tstep+2 (a full step of slack)
            if (tstep + 2 < T) {
                const int tn = tstep + 2;
                const f16x8* np = (const f16x8*)(&ins[(tn >> 4) & 1][tn & 15][k0i]);
#pragma unroll
                for (int i = 0; i < 4; ++i) ip[cur ^ 1][i] = np[i];
            }

            // (4) rec reduce + gates
            sz = quad_sum(sz); sr = quad_sum(sr); sh = quad_sum(sh);
            const float z  = fsigmoid(xz + sz);
            const float r  = fsigmoid(xr + sr);
            const float hh = ftanh_(xh + (sh + bhR) * r);
            const float hn = fmaf(z, h_old - hh, hh);
            h_old = hn;

            // (5) writes
            if (kh == 0) {
                hb[rbuf ^ 1][j] = (_Float16)hn;
                hob[(size_t)tstep * HID + j] = (_Float16)hn;
            }
            if (ts == 7 && c + 1 < NC) stage_write(c + 1);  // loads ~7 steps old

            // (6) proj reduce -> next step's xz/xr/xh
            if (tstep + 1 < T) {
                xz = quad_sum(pz) + bzK;
                xr = quad_sum(pr) + brK;
                xh = quad_sum(ph) + bhK;
            }

            soft_barrier();   // lgkm-only: global loads/stores stay in flight
        }
    }

    // final publish
    __syncthreads();
    if (t == 0 && layer < 2)
        __hip_atomic_store(myflag, T, __ATOMIC_RELEASE, __HIP_MEMORY_SCOPE_AGENT);
}

// ---------------------------------------------------------------------------
// out_proj: out[r,:] = h_f16[r,:] @ wo + bo (fp32 out). Thread = row.
// ---------------------------------------------------------------------------
__global__ __launch_bounds__(256) void out_proj(
    const _Float16* __restrict__ Hf,  // [R,128] f16
    const float* __restrict__ wo,     // [128,5]
    const float* __restrict__ bo,     // [5]
    float*       __restrict__ out,    // [R,5]
    int R)
{
    const int r = blockIdx.x * 256 + threadIdx.x;
    if (r >= R) return;
    const f16x8* xp = (const f16x8*)(Hf + (size_t)r * HID);

    float a0 = bo[0], a1 = bo[1], a2 = bo[2], a3 = bo[3], a4 = bo[4];
#pragma unroll 4
    for (int c = 0; c < 16; ++c) {
        const f16x8 v = xp[c];
#pragma unroll
        for (int e = 0; e < 8; ++e) {
            const float xv = (float)v[e];
            const float* w = wo + (size_t)(8 * c + e) * OUTD;
            a0 = fmaf(xv, w[0], a0);
            a1 = fmaf(xv, w[1], a1);
            a2 = fmaf(xv, w[2], a2);
            a3 = fmaf(xv, w[3], a3);
            a4 = fmaf(xv, w[4], a4);
        }
    }
    float* op = out + (size_t)r * OUTD;
    op[0] = a0; op[1] = a1; op[2] = a2; op[3] = a3; op[4] = a4;
}

// ---------------------------------------------------------------------------
extern "C" void kernel_launch(void* const* d_in, const int* in_sizes, int n_in,
                              void* d_out, int out_size, void* d_ws, size_t ws_size,
                              hipStream_t stream) {
    const float* x   = (const float*)d_in[0];
    const float* k0  = (const float*)d_in[1];
    const float* rk0 = (const float*)d_in[2];
    const float* b0  = (const float*)d_in[3];
    const float* k1  = (const float*)d_in[4];
    const float* rk1 = (const float*)d_in[5];
    const float* b1  = (const float*)d_in[6];
    const float* k2  = (const float*)d_in[7];
    const float* rk2 = (const float*)d_in[8];
    const float* b2  = (const float*)d_in[9];
    const float* wo  = (const float*)d_in[10];
    const float* bo  = (const float*)d_in[11];
    float* out = (float*)d_out;

    const int BT = in_sizes[0] / HID;   // 64*2048 = 131072 rows
    const int B  = 64;
    const int T  = BT / B;              // 2048

    // ws layout: 3 f16 h-planes (32MB each) + flags
    const size_t plane = (size_t)BT * HID * sizeof(_Float16);
    _Float16* hpl0 = (_Float16*)d_ws;
    _Float16* hpl1 = (_Float16*)((char*)d_ws + plane);
    _Float16* hpl2 = (_Float16*)((char*)d_ws + 2 * plane);
    int*      flags = (int*)((char*)d_ws + 3 * plane);

    zero_flags<<<1, 256, 0, stream>>>(flags);
    gru_pipe  <<<192, 512, 0, stream>>>(x, k0, k1, k2, rk0, rk1, rk2,
                                        b0, b1, b2, hpl0, hpl1, hpl2, flags, T);
    out_proj  <<<(BT + 255) / 256, 256, 0, stream>>>(hpl2, wo, bo, out, BT);
}